// Round 1
// baseline (1433.324 us; speedup 1.0000x reference)
//
#include <hip/hip_runtime.h>
#include <stdint.h>

// Problem constants (ReIdHead): B=256 queries, D=256, N=500000, labels<1000.
#define BQ 256
#define DD 256
#define EPS 1e-8f

#define NTILE 128          // db rows per block-tile
#define BK    32           // K-step
#define APITCH 260         // 256+4 pad (bank-conflict-free b128 reads)
#define BPITCH 132         // 128+4 pad
#define MAXBLK 2048        // partial-result slots per query

// ---- sortable float key: monotone uint32, argmax-with-lowest-index via ~idx ----
__device__ __forceinline__ uint32_t f2key(float f) {
  uint32_t u = __float_as_uint(f);
  return (u & 0x80000000u) ? ~u : (u | 0x80000000u);
}
__device__ __forceinline__ float key2f(uint32_t k) {
  uint32_t u = (k & 0x80000000u) ? (k & 0x7FFFFFFFu) : ~k;
  return __uint_as_float(u);
}

// ---- kernel 1: normalize queries (one wave per query) ----
__global__ void norm_q(const float* __restrict__ q, float* __restrict__ qn) {
  const int b = blockIdx.x;
  const int lane = threadIdx.x;           // 64 threads
  float4 v = *(const float4*)&q[b * DD + lane * 4];
  float ss = v.x * v.x + v.y * v.y + v.z * v.z + v.w * v.w;
#pragma unroll
  for (int off = 32; off; off >>= 1) ss += __shfl_xor(ss, off);
  float inv = 1.0f / fmaxf(sqrtf(ss), EPS);
  float4 o = make_float4(v.x * inv, v.y * inv, v.z * inv, v.w * inv);
  *(float4*)&qn[b * DD + lane * 4] = o;
}

// ---- kernel 2: fused fp32 GEMM (256q x 128n per tile) + db-norm + block argmax ----
// thread layout: 256 threads, tx = tid&15 (n side), ty = tid>>4 (q side)
// per-thread micro-tile: q = g*64 + ty*4 + u (g<4,u<4), n = n0 + h*64 + tx*4 + j (h<2,j<4)
__global__ __launch_bounds__(256, 2)
void gemm_argmax(const float* __restrict__ db, const float* __restrict__ qn,
                 unsigned long long* __restrict__ part, int N, int ntiles, int nblk) {
  __shared__ float As[BK][APITCH];     // K-major, padded
  __shared__ float Bs[BK][BPITCH];
  __shared__ float normLDS[NTILE];

  const int tid = threadIdx.x;
  const int tx = tid & 15, ty = tid >> 4;

  unsigned long long best[4][4];
#pragma unroll
  for (int g = 0; g < 4; ++g)
#pragma unroll
    for (int u = 0; u < 4; ++u) best[g][u] = 0ull;

  for (int tile = blockIdx.x; tile < ntiles; tile += nblk) {
    const int n0 = tile * NTILE;
    const bool fullTile = (n0 + NTILE <= N);

    float acc[4][4][2][4];
#pragma unroll
    for (int g = 0; g < 4; ++g)
#pragma unroll
      for (int u = 0; u < 4; ++u)
#pragma unroll
        for (int h = 0; h < 2; ++h)
#pragma unroll
          for (int j = 0; j < 4; ++j) acc[g][u][h][j] = 0.f;

    float nrm[2][4];
#pragma unroll
    for (int h = 0; h < 2; ++h)
#pragma unroll
      for (int j = 0; j < 4; ++j) nrm[h][j] = 0.f;

    for (int ks = 0; ks < DD / BK; ++ks) {
      const int k0 = ks * BK;
      __syncthreads();   // previous LDS readers done
      // stage A (q_n): 2048 float4 -> 8 per thread, transposed scalar writes
#pragma unroll
      for (int i = 0; i < 8; ++i) {
        int f = tid + i * 256;
        int qq = f >> 3, c4 = f & 7;
        float4 v = *(const float4*)&qn[qq * DD + k0 + c4 * 4];
        As[c4 * 4 + 0][qq] = v.x;
        As[c4 * 4 + 1][qq] = v.y;
        As[c4 * 4 + 2][qq] = v.z;
        As[c4 * 4 + 3][qq] = v.w;
      }
      // stage B (db): 1024 float4 -> 4 per thread
#pragma unroll
      for (int i = 0; i < 4; ++i) {
        int f = tid + i * 256;
        int r = f >> 3, c4 = f & 7;
        float4 v;
        if (fullTile || (n0 + r) < N)
          v = *(const float4*)&db[(size_t)(n0 + r) * DD + k0 + c4 * 4];
        else
          v = make_float4(0.f, 0.f, 0.f, 0.f);
        Bs[c4 * 4 + 0][r] = v.x;
        Bs[c4 * 4 + 1][r] = v.y;
        Bs[c4 * 4 + 2][r] = v.z;
        Bs[c4 * 4 + 3][r] = v.w;
      }
      __syncthreads();
      // inner K loop
#pragma unroll 4
      for (int k = 0; k < BK; ++k) {
        float a[16], b[8];
#pragma unroll
        for (int g = 0; g < 4; ++g) {
          float4 va = *(const float4*)&As[k][g * 64 + ty * 4];
          a[g * 4 + 0] = va.x; a[g * 4 + 1] = va.y;
          a[g * 4 + 2] = va.z; a[g * 4 + 3] = va.w;
        }
#pragma unroll
        for (int h = 0; h < 2; ++h) {
          float4 vb = *(const float4*)&Bs[k][h * 64 + tx * 4];
          b[h * 4 + 0] = vb.x; b[h * 4 + 1] = vb.y;
          b[h * 4 + 2] = vb.z; b[h * 4 + 3] = vb.w;
        }
#pragma unroll
        for (int g = 0; g < 4; ++g)
#pragma unroll
          for (int u = 0; u < 4; ++u)
#pragma unroll
            for (int h = 0; h < 2; ++h)
#pragma unroll
              for (int j = 0; j < 4; ++j)
                acc[g][u][h][j] = fmaf(a[g * 4 + u], b[h * 4 + j], acc[g][u][h][j]);
        if (ty == 0) {
#pragma unroll
          for (int h = 0; h < 2; ++h)
#pragma unroll
            for (int j = 0; j < 4; ++j)
              nrm[h][j] = fmaf(b[h * 4 + j], b[h * 4 + j], nrm[h][j]);
        }
      }
    }
    // epilogue: share db norms, normalize, block-local argmax
    __syncthreads();
    if (ty == 0) {
#pragma unroll
      for (int h = 0; h < 2; ++h)
#pragma unroll
        for (int j = 0; j < 4; ++j) normLDS[h * 64 + tx * 4 + j] = nrm[h][j];
    }
    __syncthreads();
    float inv[2][4];
#pragma unroll
    for (int h = 0; h < 2; ++h)
#pragma unroll
      for (int j = 0; j < 4; ++j) {
        float ns = normLDS[h * 64 + tx * 4 + j];
        inv[h][j] = 1.0f / fmaxf(sqrtf(ns), EPS);
      }
#pragma unroll
    for (int g = 0; g < 4; ++g) {
#pragma unroll
      for (int u = 0; u < 4; ++u) {
        unsigned long long loc = 0ull;
#pragma unroll
        for (int h = 0; h < 2; ++h)
#pragma unroll
          for (int j = 0; j < 4; ++j) {
            int n = n0 + h * 64 + tx * 4 + j;
            float sim = acc[g][u][h][j] * inv[h][j];
            unsigned long long p =
                ((unsigned long long)f2key(sim) << 32) |
                (unsigned long long)(0xFFFFFFFFu - (uint32_t)n);
            bool valid = fullTile || (n < N);
            if (valid && p > loc) loc = p;
          }
        // reduce across the 16 tx lanes of this ty row
#pragma unroll
        for (int off = 1; off < 16; off <<= 1) {
          unsigned long long o = __shfl_xor(loc, off);
          if (o > loc) loc = o;
        }
        if (loc > best[g][u]) best[g][u] = loc;
      }
    }
  }
  if (tx == 0) {
#pragma unroll
    for (int g = 0; g < 4; ++g)
#pragma unroll
      for (int u = 0; u < 4; ++u) {
        int qq = g * 64 + ty * 4 + u;
        part[(size_t)qq * nblk + blockIdx.x] = best[g][u];
      }
  }
}

// ---- kernel 3: final reduce per query + label gather ----
__global__ void finalize(const unsigned long long* __restrict__ part,
                         const int* __restrict__ labels, float* __restrict__ out,
                         int nblk) {
  const int q = blockIdx.x;
  const int t = threadIdx.x;     // 256 threads
  unsigned long long loc = 0ull;
  for (int i = t; i < nblk; i += 256) {
    unsigned long long v = part[(size_t)q * nblk + i];
    if (v > loc) loc = v;
  }
#pragma unroll
  for (int off = 1; off < 64; off <<= 1) {
    unsigned long long o = __shfl_xor(loc, off);
    if (o > loc) loc = o;
  }
  __shared__ unsigned long long red[4];
  if ((t & 63) == 0) red[t >> 6] = loc;
  __syncthreads();
  if (t == 0) {
    unsigned long long m = red[0];
    for (int w = 1; w < 4; ++w)
      if (red[w] > m) m = red[w];
    uint32_t key = (uint32_t)(m >> 32);
    uint32_t idx = 0xFFFFFFFFu - (uint32_t)(m & 0xFFFFFFFFu);
    out[q] = key2f(key);
    out[BQ + q] = (float)labels[idx];
  }
}

extern "C" void kernel_launch(void* const* d_in, const int* in_sizes, int n_in,
                              void* d_out, int out_size, void* d_ws, size_t ws_size,
                              hipStream_t stream) {
  const float* q      = (const float*)d_in[0];   // [256,256] f32
  const float* db     = (const float*)d_in[1];   // [500000,256] f32
  const int*   labels = (const int*)d_in[2];     // [500000] int32
  float* out = (float*)d_out;                    // [512]: top_sim ++ labels-as-float

  const int N = in_sizes[2];
  const int ntiles = (N + NTILE - 1) / NTILE;
  const int nblk = ntiles < MAXBLK ? ntiles : MAXBLK;

  float* qn = (float*)d_ws;                                      // 256 KiB
  unsigned long long* part =
      (unsigned long long*)((char*)d_ws + (size_t)BQ * DD * 4);  // 256*nblk*8 <= 4 MiB

  norm_q<<<BQ, 64, 0, stream>>>(q, qn);
  gemm_argmax<<<nblk, 256, 0, stream>>>(db, qn, part, N, ntiles, nblk);
  finalize<<<BQ, 256, 0, stream>>>(part, labels, out, nblk);
}